// Round 6
// baseline (150.155 us; speedup 1.0000x reference)
//
#include <hip/hip_runtime.h>

// Unfold (im2col) x: [16, 64, 128, 128] f32, K=3, pad=1.
// out[(b*64+c)*9 + m][y][x] = in[b,c, y + m/3 - 1, x + m%3 - 1], 0 if OOB.
// R6: R5 structure, but PLAIN stores (A/B vs nontemporal hint). Everything
// else identical: 1 float4 load + 2 shuffles -> 3 float4 stores per triplet.

typedef float f32x4 __attribute__((ext_vector_type(4)));

__global__ __launch_bounds__(256) void unfold_kernel(
    const float* __restrict__ in, float* __restrict__ out) {
    constexpr int H = 128, W = 128;
    constexpr int W4 = W / 4;         // 32 float4 per row
    constexpr int PLANE4 = H * W / 4; // 4096 float4 per plane

    const int blk = blockIdx.x;      // 0 .. 2047
    const int half = blk & 1;
    const int bc = blk >> 1;         // b*64 + c

    const float* plane_in = in + (size_t)bc * (H * W);
    f32x4* plane_out = reinterpret_cast<f32x4*>(out) + (size_t)bc * 9 * PLANE4;

    const int tid = threadIdx.x;
    const int xq = tid & (W4 - 1);   // 0..31
    const int r0 = tid >> 5;         // 0..7

    for (int g = 0; g < 8; ++g) {             // 8 groups x 8 rows = 64 rows
        const int r = half * 64 + g * 8 + r0; // output row
        #pragma unroll
        for (int di = -1; di <= 1; ++di) {
            const int ry = r + di;
            f32x4 a = (f32x4)(0.f);
            if ((unsigned)ry < (unsigned)H) {
                a = reinterpret_cast<const f32x4*>(plane_in + ry * W)[xq];
            }
            // edge values from neighbor lanes within the 32-lane row group
            float left  = __shfl_up(a.w, 1, 32);
            float right = __shfl_down(a.x, 1, 32);
            if (xq == 0)      left  = 0.f;   // x = -1 pad
            if (xq == W4 - 1) right = 0.f;   // x = 128 pad
            f32x4 vm1; vm1.x = left; vm1.y = a.x; vm1.z = a.y; vm1.w = a.z; // dj=-1
            f32x4 vp1; vp1.x = a.y; vp1.y = a.z; vp1.z = a.w; vp1.w = right; // dj=+1
            const int mbase = (di + 1) * 3;
            const size_t o = (size_t)r * W4 + xq;
            plane_out[(size_t)(mbase + 0) * PLANE4 + o] = vm1;
            plane_out[(size_t)(mbase + 1) * PLANE4 + o] = a;
            plane_out[(size_t)(mbase + 2) * PLANE4 + o] = vp1;
        }
    }
}

extern "C" void kernel_launch(void* const* d_in, const int* in_sizes, int n_in,
                              void* d_out, int out_size, void* d_ws, size_t ws_size,
                              hipStream_t stream) {
    const float* in = (const float*)d_in[0];
    float* out = (float*)d_out;
    // 16*64 planes x 2 halves = 2048 blocks, 256 threads each.
    unfold_kernel<<<2048, 256, 0, stream>>>(in, out);
}

// Round 7
// 114.155 us; speedup vs baseline: 1.3154x; 1.3154x over previous
//
#include <hip/hip_runtime.h>

// Unfold (im2col) x: [16, 64, 128, 128] f32, K=3, pad=1.
// out[(b*64+c)*9 + m][y][x] = in[b,c, y + m/3 - 1, x + m%3 - 1], 0 if OOB.
// R7: R5 structure (nt stores + shuffle edges — both verified by A/B).
// Change: plane pair decomposition (k, k+1024) instead of (2k, 2k+1) so both
// half-plane blocks of one input plane land on the SAME XCD (1024 % 8 == 0)
// -> input L2-shared instead of fetched into two XCD L2s.

typedef float f32x4 __attribute__((ext_vector_type(4)));

__global__ __launch_bounds__(256) void unfold_kernel(
    const float* __restrict__ in, float* __restrict__ out) {
    constexpr int H = 128, W = 128;
    constexpr int W4 = W / 4;         // 32 float4 per row
    constexpr int PLANE4 = H * W / 4; // 4096 float4 per plane

    const int blk = blockIdx.x;      // 0 .. 2047
    const int half = blk >> 10;      // 0 or 1
    const int bc = blk & 1023;       // b*64 + c

    const float* plane_in = in + (size_t)bc * (H * W);
    f32x4* plane_out = reinterpret_cast<f32x4*>(out) + (size_t)bc * 9 * PLANE4;

    const int tid = threadIdx.x;
    const int xq = tid & (W4 - 1);   // 0..31
    const int r0 = tid >> 5;         // 0..7

    for (int g = 0; g < 8; ++g) {             // 8 groups x 8 rows = 64 rows
        const int r = half * 64 + g * 8 + r0; // output row
        #pragma unroll
        for (int di = -1; di <= 1; ++di) {
            const int ry = r + di;
            f32x4 a = (f32x4)(0.f);
            if ((unsigned)ry < (unsigned)H) {
                a = reinterpret_cast<const f32x4*>(plane_in + ry * W)[xq];
            }
            // edge values from neighbor lanes within the 32-lane row group
            float left  = __shfl_up(a.w, 1, 32);
            float right = __shfl_down(a.x, 1, 32);
            if (xq == 0)      left  = 0.f;   // x = -1 pad
            if (xq == W4 - 1) right = 0.f;   // x = 128 pad
            f32x4 vm1; vm1.x = left; vm1.y = a.x; vm1.z = a.y; vm1.w = a.z; // dj=-1
            f32x4 vp1; vp1.x = a.y; vp1.y = a.z; vp1.z = a.w; vp1.w = right; // dj=+1
            const int mbase = (di + 1) * 3;
            const size_t o = (size_t)r * W4 + xq;
            __builtin_nontemporal_store(vm1, &plane_out[(size_t)(mbase + 0) * PLANE4 + o]);
            __builtin_nontemporal_store(a,   &plane_out[(size_t)(mbase + 1) * PLANE4 + o]);
            __builtin_nontemporal_store(vp1, &plane_out[(size_t)(mbase + 2) * PLANE4 + o]);
        }
    }
}

extern "C" void kernel_launch(void* const* d_in, const int* in_sizes, int n_in,
                              void* d_out, int out_size, void* d_ws, size_t ws_size,
                              hipStream_t stream) {
    const float* in = (const float*)d_in[0];
    float* out = (float*)d_out;
    // 16*64 planes x 2 halves = 2048 blocks, 256 threads each.
    unfold_kernel<<<2048, 256, 0, stream>>>(in, out);
}